// Round 12
// baseline (37.575 us; speedup 1.0000x reference)
//
#include <hip/hip_runtime.h>

#define MARGIN 0.2f
#define EPSF   1e-16f

constexpr int BSZ   = 512;    // batch
constexpr int DIM   = 1024;   // embedding dim
constexpr int NPROD = 1024;   // producer blocks (one 16x16 tile each)
constexpr int NRED  = 128;    // reducer role count (4 anchors each)

typedef __attribute__((ext_vector_type(8))) short    bf16x8;
typedef __attribute__((ext_vector_type(4))) unsigned uint4v;
typedef __attribute__((ext_vector_type(4))) float    f32x4;

// 8x f32 -> 8x bf16 via v_cvt_pk_bf16_f32 (RNE). A and B use the same packing;
// dot products are k-permutation invariant, so in-lane order is free.
__device__ __forceinline__ bf16x8 cvt8(float4 a, float4 b) {
    uint4v u;
    asm("v_cvt_pk_bf16_f32 %0, %1, %2" : "=v"(u[0]) : "v"(a.x), "v"(a.y));
    asm("v_cvt_pk_bf16_f32 %0, %1, %2" : "=v"(u[1]) : "v"(a.z), "v"(a.w));
    asm("v_cvt_pk_bf16_f32 %0, %1, %2" : "=v"(u[2]) : "v"(b.x), "v"(b.y));
    asm("v_cvt_pk_bf16_f32 %0, %1, %2" : "=v"(u[3]) : "v"(b.z), "v"(b.w));
    return __builtin_bit_cast(bf16x8, u);
}

// ---------------- Single fused kernel -----------------
// Phase A (all 1024 blocks): R8 GEMM tile -> pw via agent-scope atomic
//   stores (write-through, cross-XCD visible), vmcnt-acked relaxed gate RMW.
// Phase B (last 128 finishers): spin gate==1024, R11 reduce of 4 anchors,
//   packed partial store + ctr2 RMW; 128th reducer finalizes to out.
__global__ void __launch_bounds__(256) fused_all(const float* __restrict__ I,
                                                 const float* __restrict__ S,
                                                 const int*   __restrict__ labels,
                                                 float* __restrict__ pw,
                                                 unsigned* __restrict__ ctr,   // [0]=gate, [1]=fin
                                                 unsigned long long* __restrict__ part,
                                                 float* __restrict__ out) {
    __shared__ f32x4 cpart[3][64];
    __shared__ int   lab[BSZ];
    __shared__ __align__(16) float rows[4][BSZ];
    __shared__ float wsum_s[4];
    __shared__ int   wcnt_s[4];
    __shared__ unsigned role;

    const int tid  = threadIdx.x;
    const int lane = tid & 63;
    const int w    = tid >> 6;                       // K quarter 0..3
    const int tile = ((blockIdx.x & 7) << 7) | (blockIdx.x >> 3);  // bijective
    const int tr   = (tile >> 5) * 16;
    const int tc   = (tile & 31) * 16;
    const int r    = lane & 15;
    const int ko   = (lane >> 4) * 8;

    // ---- Phase A: MFMA GEMM (R8 structure) ----
    const float* Ab = I + (size_t)(tr + r) * DIM + w * 256 + ko;
    const float* Bb = S + (size_t)(tc + r) * DIM + w * 256 + ko;

    f32x4 acc0 = {0.f, 0.f, 0.f, 0.f};
    f32x4 acc1 = {0.f, 0.f, 0.f, 0.f};
#pragma unroll
    for (int t = 0; t < 8; t += 2) {                 // 8 k-steps, 2 acc chains
        acc0 = __builtin_amdgcn_mfma_f32_16x16x32_bf16(
                   cvt8(*(const float4*)(Ab + t * 32),      *(const float4*)(Ab + t * 32 + 4)),
                   cvt8(*(const float4*)(Bb + t * 32),      *(const float4*)(Bb + t * 32 + 4)),
                   acc0, 0, 0, 0);
        acc1 = __builtin_amdgcn_mfma_f32_16x16x32_bf16(
                   cvt8(*(const float4*)(Ab + t * 32 + 32), *(const float4*)(Ab + t * 32 + 36)),
                   cvt8(*(const float4*)(Bb + t * 32 + 32), *(const float4*)(Bb + t * 32 + 36)),
                   acc1, 0, 0, 0);
    }
    acc0 += acc1;

    if (w) cpart[w - 1][lane] = acc0;
    __syncthreads();
    if (w == 0) {
        acc0 += cpart[0][lane];
        acc0 += cpart[1][lane];
        acc0 += cpart[2][lane];
        const int orow = tr + (lane >> 4) * 4;
        const int ocol = tc + r;
#pragma unroll
        for (int q = 0; q < 4; ++q)
            __hip_atomic_store(&pw[(orow + q) * BSZ + ocol], acc0[q],
                               __ATOMIC_RELAXED, __HIP_MEMORY_SCOPE_AGENT);
    }

    // ---- gate: one RMW per block after its stores are performed ----
    if (tid == 0) {
        asm volatile("s_waitcnt vmcnt(0)" ::: "memory");   // wave0 stores acked
        role = __hip_atomic_fetch_add(&ctr[0], 1u, __ATOMIC_RELAXED,
                                      __HIP_MEMORY_SCOPE_AGENT);
    }
    __syncthreads();
    const unsigned old = role;
    if (old < (unsigned)(NPROD - NRED)) return;       // early blocks exit
    const int g = (int)old - (NPROD - NRED);          // reducer id 0..127

    if (tid == 0) {
        while (__hip_atomic_load(&ctr[0], __ATOMIC_RELAXED,
                                 __HIP_MEMORY_SCOPE_AGENT) < (unsigned)NPROD)
            __builtin_amdgcn_s_sleep(2);
    }
    __syncthreads();
    asm volatile("" ::: "memory");

    // ---- Phase B: reduce anchors [g*4, g*4+4) (R11 body) ----
    const int a0 = g * 4;
    if (tid < 128) ((int4*)lab)[tid] = ((const int4*)labels)[tid];
    {
        unsigned long long*       rp = (unsigned long long*)rows;
        const unsigned long long* gp = (const unsigned long long*)(pw + (size_t)a0 * BSZ);
#pragma unroll
        for (int j = 0; j < 4; ++j) {
            const unsigned long long v =
                __hip_atomic_load(&gp[tid + j * 256], __ATOMIC_RELAXED,
                                  __HIP_MEMORY_SCOPE_AGENT);
            rp[tid + j * 256] = v;
        }
    }
    __syncthreads();

    const int la = lab[a0 + w];
    float vn[8];
    bool  ng[8];
#pragma unroll
    for (int j = 0; j < 8; ++j) {
        const int n = j * 64 + lane;
        vn[j] = rows[w][n];
        ng[j] = (lab[n] != la);
    }

    float sum = 0.f;
    int   cnt = 0;
    for (int p0 = 0; p0 < BSZ; p0 += 64) {
        unsigned long long m = __ballot(lab[p0 + lane] == la);
        while (m) {                                   // ascending p, uniform
            const int p = p0 + __ffsll((long long)m) - 1;
            m &= m - 1;
            const float pv = rows[w][p] + MARGIN;     // LDS broadcast
#pragma unroll
            for (int j = 0; j < 8; ++j) {
                const float v = pv - vn[j];
                sum += ng[j] ? fmaxf(v, 0.f) : 0.f;
                cnt += (ng[j] && v > EPSF) ? 1 : 0;
            }
        }
    }

#pragma unroll
    for (int off = 32; off > 0; off >>= 1) {
        sum += __shfl_down(sum, off);
        cnt += __shfl_down(cnt, off);
    }
    if (lane == 0) { wsum_s[w] = sum; wcnt_s[w] = cnt; }
    __syncthreads();

    if (tid == 0) {
        const float s = wsum_s[0] + wsum_s[1] + wsum_s[2] + wsum_s[3];
        const float c = (float)(wcnt_s[0] + wcnt_s[1] + wcnt_s[2] + wcnt_s[3]);
        const float2 pk2 = make_float2(s, c);
        __hip_atomic_store(&part[g], __builtin_bit_cast(unsigned long long, pk2),
                           __ATOMIC_RELAXED, __HIP_MEMORY_SCOPE_AGENT);
        asm volatile("s_waitcnt vmcnt(0)" ::: "memory");
        role = __hip_atomic_fetch_add(&ctr[1], 1u, __ATOMIC_RELAXED,
                                      __HIP_MEMORY_SCOPE_AGENT);
    }
    __syncthreads();

    if (role == (unsigned)(NRED - 1)) {               // 128th reducer finalizes
        float s = 0.f, c = 0.f;
        if (tid < NRED) {
            const unsigned long long v =
                __hip_atomic_load(&part[tid], __ATOMIC_RELAXED,
                                  __HIP_MEMORY_SCOPE_AGENT);
            const float2 f = __builtin_bit_cast(float2, v);
            s = f.x;
            c = f.y;
        }
#pragma unroll
        for (int off = 32; off > 0; off >>= 1) {
            s += __shfl_down(s, off);
            c += __shfl_down(c, off);
        }
        if (lane == 0) { wsum_s[w] = s; wcnt_s[w] = (int)c; }
        __syncthreads();
        if (tid == 0) {
            const float S_ = wsum_s[0] + wsum_s[1] + wsum_s[2] + wsum_s[3];
            const float C_ = (float)(wcnt_s[0] + wcnt_s[1] + wcnt_s[2] + wcnt_s[3]);
            out[0] = S_ / (C_ + EPSF);
        }
    }
}

extern "C" void kernel_launch(void* const* d_in, const int* in_sizes, int n_in,
                              void* d_out, int out_size, void* d_ws, size_t ws_size,
                              hipStream_t stream) {
    const int*   labels = (const int*)d_in[0];
    const float* img    = (const float*)d_in[1];
    const float* sen    = (const float*)d_in[2];
    float* out = (float*)d_out;

    // ws layout: ctr[2] (memset to 0), pw (1 MB), packed partials (1 KB)
    unsigned*           ctr  = (unsigned*)d_ws;
    float*              pw   = (float*)((char*)d_ws + 256);
    unsigned long long* part = (unsigned long long*)((char*)d_ws + 256 + (1u << 20));

    hipMemsetAsync(d_ws, 0, 8, stream);
    fused_all<<<NPROD, 256, 0, stream>>>(img, sen, labels, pw, ctr, part, out);
}

// Round 13
// 19.660 us; speedup vs baseline: 1.9112x; 1.9112x over previous
//
#include <hip/hip_runtime.h>

#define MARGIN 0.2f
#define EPSF   1e-16f

constexpr int BSZ  = 512;   // batch
constexpr int DIM  = 1024;  // embedding dim
constexpr int RBLK = 128;   // reduce blocks (4 anchors each)

typedef __attribute__((ext_vector_type(8))) short    bf16x8;
typedef __attribute__((ext_vector_type(4))) unsigned uint4v;
typedef __attribute__((ext_vector_type(4))) float    f32x4;

// 8x f32 -> 8x bf16 via v_cvt_pk_bf16_f32 (RNE). A and B use the same packing;
// dot products are k-permutation invariant, so in-lane order is free.
__device__ __forceinline__ bf16x8 cvt8(float4 a, float4 b) {
    uint4v u;
    asm("v_cvt_pk_bf16_f32 %0, %1, %2" : "=v"(u[0]) : "v"(a.x), "v"(a.y));
    asm("v_cvt_pk_bf16_f32 %0, %1, %2" : "=v"(u[1]) : "v"(a.z), "v"(a.w));
    asm("v_cvt_pk_bf16_f32 %0, %1, %2" : "=v"(u[2]) : "v"(b.x), "v"(b.y));
    asm("v_cvt_pk_bf16_f32 %0, %1, %2" : "=v"(u[3]) : "v"(b.z), "v"(b.w));
    return __builtin_bit_cast(bf16x8, u);
}

// ---------------- Node 1: MFMA GEMM, 32x32 tile/block, K split 4 ways -------
// 256 blocks x 4 waves. Each block owns one 32x32 C tile (2x2 16x16
// fragments); wave w covers k in [w*256, w*256+256) (8 k-steps) for ALL four
// fragments -> per-block L2 reads = 64 rows * 4 KB = 256 KB for 4 tiles
// (64 KB/tile, half of the 16x16-tile structure). Fixed-order LDS combine
// ((w0+w1)+w2)+w3 keeps pw bit-identical to R8/R11. XCD-bijective swizzle.
// Block 0 zeroes ctr for node 2's last-block finalize.
// mfma_f32_16x16x32_bf16: A/B row|col = lane&15, k = (lane>>4)*8 + j;
// C/D: col = lane&15, row = (lane>>4)*4 + q.
__global__ void __launch_bounds__(256) mfma_gemm(const float* __restrict__ I,
                                                 const float* __restrict__ S,
                                                 float* __restrict__ pw,
                                                 unsigned* __restrict__ ctr) {
    __shared__ f32x4 part[3][4][64];

    const int tid  = threadIdx.x;
    const int lane = tid & 63;
    const int w    = tid >> 6;                       // K quarter 0..3
    const int tile = ((blockIdx.x & 7) << 5) | (blockIdx.x >> 3);  // bijective
    const int tr   = (tile >> 4) * 32;               // anchor base
    const int tc   = (tile & 15) * 32;               // negative base
    const int r    = lane & 15;
    const int ko   = (lane >> 4) * 8;

    if (blockIdx.x == 0 && tid == 0) *ctr = 0u;

    const float* A0 = I + (size_t)(tr + r)      * DIM + w * 256 + ko;
    const float* A1 = I + (size_t)(tr + 16 + r) * DIM + w * 256 + ko;
    const float* B0 = S + (size_t)(tc + r)      * DIM + w * 256 + ko;
    const float* B1 = S + (size_t)(tc + 16 + r) * DIM + w * 256 + ko;

    f32x4 a00 = {0.f, 0.f, 0.f, 0.f};
    f32x4 a01 = {0.f, 0.f, 0.f, 0.f};
    f32x4 a10 = {0.f, 0.f, 0.f, 0.f};
    f32x4 a11 = {0.f, 0.f, 0.f, 0.f};
#pragma unroll
    for (int t = 0; t < 8; ++t) {                    // 8 k-steps, 4 acc chains
        const bf16x8 fa0 = cvt8(*(const float4*)(A0 + t * 32), *(const float4*)(A0 + t * 32 + 4));
        const bf16x8 fa1 = cvt8(*(const float4*)(A1 + t * 32), *(const float4*)(A1 + t * 32 + 4));
        const bf16x8 fb0 = cvt8(*(const float4*)(B0 + t * 32), *(const float4*)(B0 + t * 32 + 4));
        const bf16x8 fb1 = cvt8(*(const float4*)(B1 + t * 32), *(const float4*)(B1 + t * 32 + 4));
        a00 = __builtin_amdgcn_mfma_f32_16x16x32_bf16(fa0, fb0, a00, 0, 0, 0);
        a01 = __builtin_amdgcn_mfma_f32_16x16x32_bf16(fa0, fb1, a01, 0, 0, 0);
        a10 = __builtin_amdgcn_mfma_f32_16x16x32_bf16(fa1, fb0, a10, 0, 0, 0);
        a11 = __builtin_amdgcn_mfma_f32_16x16x32_bf16(fa1, fb1, a11, 0, 0, 0);
    }

    if (w) {
        part[w - 1][0][lane] = a00;
        part[w - 1][1][lane] = a01;
        part[w - 1][2][lane] = a10;
        part[w - 1][3][lane] = a11;
    }
    __syncthreads();
    if (w == 0) {
        f32x4 q[4] = {a00, a01, a10, a11};
#pragma unroll
        for (int i = 0; i < 4; ++i) {                // fixed order: +w1+w2+w3
            q[i] += part[0][i][lane];
            q[i] += part[1][i][lane];
            q[i] += part[2][i][lane];
        }
        const int orow = tr + (lane >> 4) * 4;
        const int ocol = tc + r;
#pragma unroll
        for (int qm = 0; qm < 2; ++qm)
#pragma unroll
            for (int qn = 0; qn < 2; ++qn) {
                const f32x4 v = q[qm * 2 + qn];
#pragma unroll
                for (int e = 0; e < 4; ++e)
                    pw[(orow + qm * 16 + e) * BSZ + (ocol + qn * 16)] = v[e];
            }
    }
}

// ---------------- Node 2: 4-anchor triplet reduce + de-contended finalize ---
// (R11 verbatim.) 128 blocks x 256 thr; wave w owns anchor 4*blk+w. Ballot-
// walked positives (ascending p), register-cached negatives. One packed
// agent-scope atomic store per block + vmcnt-acked relaxed ctr RMW; last
// block (old==127) loads 128 partials and finalizes.
__global__ void __launch_bounds__(256) triplet_reduce(const float* __restrict__ pw,
                                                      const int*   __restrict__ labels,
                                                      unsigned long long* __restrict__ part,
                                                      unsigned* __restrict__ ctr,
                                                      float* __restrict__ out) {
    __shared__ int   lab[BSZ];
    __shared__ float rows[4][BSZ];
    __shared__ float wsum_s[4];
    __shared__ int   wcnt_s[4];
    __shared__ unsigned is_last;

    const int tid  = threadIdx.x;
    const int lane = tid & 63;
    const int w    = tid >> 6;
    const int a0   = blockIdx.x * 4;

    if (tid < 128) ((int4*)lab)[tid] = ((const int4*)labels)[tid];
    ((float4*)rows)[tid]       = ((const float4*)(pw + (size_t)a0 * BSZ))[tid];
    ((float4*)rows)[tid + 256] = ((const float4*)(pw + (size_t)a0 * BSZ))[tid + 256];
    __syncthreads();

    const int la = lab[a0 + w];

    float vn[8];
    bool  ng[8];
#pragma unroll
    for (int j = 0; j < 8; ++j) {
        const int n = j * 64 + lane;
        vn[j] = rows[w][n];
        ng[j] = (lab[n] != la);
    }

    float sum = 0.f;
    int   cnt = 0;
    for (int p0 = 0; p0 < BSZ; p0 += 64) {
        unsigned long long m = __ballot(lab[p0 + lane] == la);
        while (m) {                                   // ascending p, uniform
            const int p = p0 + __ffsll((long long)m) - 1;
            m &= m - 1;
            const float pv = rows[w][p] + MARGIN;     // LDS broadcast
#pragma unroll
            for (int j = 0; j < 8; ++j) {
                const float v = pv - vn[j];
                sum += ng[j] ? fmaxf(v, 0.f) : 0.f;
                cnt += (ng[j] && v > EPSF) ? 1 : 0;
            }
        }
    }

#pragma unroll
    for (int off = 32; off > 0; off >>= 1) {
        sum += __shfl_down(sum, off);
        cnt += __shfl_down(cnt, off);
    }
    if (lane == 0) { wsum_s[w] = sum; wcnt_s[w] = cnt; }
    __syncthreads();

    if (tid == 0) {
        const float s = wsum_s[0] + wsum_s[1] + wsum_s[2] + wsum_s[3];
        const float c = (float)(wcnt_s[0] + wcnt_s[1] + wcnt_s[2] + wcnt_s[3]);
        const float2 pk2 = make_float2(s, c);
        __hip_atomic_store(&part[blockIdx.x],
                           __builtin_bit_cast(unsigned long long, pk2),
                           __ATOMIC_RELAXED, __HIP_MEMORY_SCOPE_AGENT);
        asm volatile("s_waitcnt vmcnt(0)" ::: "memory");   // store performed
        const unsigned old = __hip_atomic_fetch_add(ctr, 1u, __ATOMIC_RELAXED,
                                                    __HIP_MEMORY_SCOPE_AGENT);
        is_last = (old == (unsigned)(RBLK - 1)) ? 1u : 0u;
    }
    __syncthreads();

    if (is_last) {                                    // 128th block: finalize
        float s = 0.f, c = 0.f;
        if (tid < RBLK) {
            const unsigned long long v =
                __hip_atomic_load(&part[tid], __ATOMIC_RELAXED,
                                  __HIP_MEMORY_SCOPE_AGENT);
            const float2 f = __builtin_bit_cast(float2, v);
            s = f.x;
            c = f.y;
        }
#pragma unroll
        for (int off = 32; off > 0; off >>= 1) {
            s += __shfl_down(s, off);
            c += __shfl_down(c, off);
        }
        if (lane == 0) { wsum_s[w] = s; wcnt_s[w] = (int)c; }
        __syncthreads();
        if (tid == 0) {
            const float S_ = wsum_s[0] + wsum_s[1] + wsum_s[2] + wsum_s[3];
            const float C_ = (float)(wcnt_s[0] + wcnt_s[1] + wcnt_s[2] + wcnt_s[3]);
            out[0] = S_ / (C_ + EPSF);
        }
    }
}

extern "C" void kernel_launch(void* const* d_in, const int* in_sizes, int n_in,
                              void* d_out, int out_size, void* d_ws, size_t ws_size,
                              hipStream_t stream) {
    const int*   labels = (const int*)d_in[0];
    const float* img    = (const float*)d_in[1];
    const float* sen    = (const float*)d_in[2];
    float* out = (float*)d_out;

    // workspace: ctr (zeroed by node 1), pw (1 MB), packed partials (1 KB)
    unsigned*           ctr  = (unsigned*)d_ws;
    float*              pw   = (float*)((char*)d_ws + 256);
    unsigned long long* part = (unsigned long long*)((char*)d_ws + 256 + (1u << 20));

    mfma_gemm<<<256, 256, 0, stream>>>(img, sen, pw, ctr);
    triplet_reduce<<<RBLK, 256, 0, stream>>>(pw, labels, part, ctr, out);
}

// Round 14
// 17.820 us; speedup vs baseline: 2.1086x; 1.1033x over previous
//
#include <hip/hip_runtime.h>

#define MARGIN 0.2f
#define EPSF   1e-16f

constexpr int BSZ  = 512;   // batch
constexpr int DIM  = 1024;  // embedding dim
constexpr int RBLK = 128;   // reduce blocks (4 anchors each)
constexpr int PWSZ = BSZ * BSZ;   // one pw partial plane (f32)

typedef __attribute__((ext_vector_type(8))) short    bf16x8;
typedef __attribute__((ext_vector_type(4))) unsigned uint4v;
typedef __attribute__((ext_vector_type(4))) float    f32x4;

// 8x f32 -> 8x bf16 via v_cvt_pk_bf16_f32 (RNE). A and B use the same packing;
// dot products are k-permutation invariant, so in-lane order is free.
__device__ __forceinline__ bf16x8 cvt8(float4 a, float4 b) {
    uint4v u;
    asm("v_cvt_pk_bf16_f32 %0, %1, %2" : "=v"(u[0]) : "v"(a.x), "v"(a.y));
    asm("v_cvt_pk_bf16_f32 %0, %1, %2" : "=v"(u[1]) : "v"(a.z), "v"(a.w));
    asm("v_cvt_pk_bf16_f32 %0, %1, %2" : "=v"(u[2]) : "v"(b.x), "v"(b.y));
    asm("v_cvt_pk_bf16_f32 %0, %1, %2" : "=v"(u[3]) : "v"(b.z), "v"(b.w));
    return __builtin_bit_cast(bf16x8, u);
}

// ---------------- Node 1: MFMA GEMM, 64x64 tile, K-quarter per block --------
// 256 blocks x 4 waves = 64 tiles x 4 K-quarters. Block (tile, kq): 4x4 16x16
// fragments over k in [kq*256, kq*256+256); wave w covers k-sub [w*64, +64)
// (2 k-steps) of ALL 128 rows -> 128 KB/block, zero intra-block redundancy.
// Cross-wave combine via LDS (fixed order w0+w1+w2+w3), each wave then stores
// 4 fragments of the block's K-partial to pw_part[kq] (written exactly once
// -> no init, no atomics; reduce sums the 4 planes in fixed order).
// XCD swizzle: xcd = bid&7 owns 8 consecutive tiles (one 64-row strip:
// A 256 KB + B 2 MB, L2-resident). Block 0 zeroes ctr for node 2.
// mfma_f32_16x16x32_bf16: A/B row|col = lane&15, k = (lane>>4)*8 + j;
// C/D: col = lane&15, row = (lane>>4)*4 + q.
__global__ void __launch_bounds__(256) mfma_gemm(const float* __restrict__ I,
                                                 const float* __restrict__ S,
                                                 float* __restrict__ pwp,
                                                 unsigned* __restrict__ ctr) {
    __shared__ f32x4 lds[4][16][64];                 // 64 KB

    const int tid  = threadIdx.x;
    const int lane = tid & 63;
    const int w    = tid >> 6;                       // K-sub 0..3 within quarter
    const int tid8 = ((blockIdx.x & 7) << 5) | (blockIdx.x >> 3);  // bijective
    const int tile = tid8 >> 2;                      // 0..63 (8x8 tile grid)
    const int kq   = tid8 & 3;                       // K quarter
    const int tr   = (tile >> 3) * 64;               // anchor base
    const int tc   = (tile & 7) * 64;                // negative base
    const int r    = lane & 15;
    const int hi   = lane >> 4;
    const int kbase = kq * 256 + w * 64 + hi * 8;

    if (blockIdx.x == 0 && tid == 0) *ctr = 0u;

    const float* Ap[4];
    const float* Bp[4];
#pragma unroll
    for (int g = 0; g < 4; ++g) {
        Ap[g] = I + (size_t)(tr + g * 16 + r) * DIM + kbase;
        Bp[g] = S + (size_t)(tc + g * 16 + r) * DIM + kbase;
    }

    f32x4 acc[4][4];
#pragma unroll
    for (int g = 0; g < 4; ++g)
#pragma unroll
        for (int h = 0; h < 4; ++h)
            acc[g][h] = (f32x4){0.f, 0.f, 0.f, 0.f};

#pragma unroll
    for (int t = 0; t < 2; ++t) {                    // 2 k-steps of 32
        bf16x8 fa[4], fb[4];
#pragma unroll
        for (int g = 0; g < 4; ++g)
            fa[g] = cvt8(*(const float4*)(Ap[g] + t * 32),
                         *(const float4*)(Ap[g] + t * 32 + 4));
#pragma unroll
        for (int h = 0; h < 4; ++h)
            fb[h] = cvt8(*(const float4*)(Bp[h] + t * 32),
                         *(const float4*)(Bp[h] + t * 32 + 4));
#pragma unroll
        for (int g = 0; g < 4; ++g)
#pragma unroll
            for (int h = 0; h < 4; ++h)
                acc[g][h] = __builtin_amdgcn_mfma_f32_16x16x32_bf16(
                                fa[g], fb[h], acc[g][h], 0, 0, 0);
    }

    // cross-wave combine (fixed order) distributed over waves
#pragma unroll
    for (int g = 0; g < 4; ++g)
#pragma unroll
        for (int h = 0; h < 4; ++h)
            lds[w][g * 4 + h][lane] = acc[g][h];
    __syncthreads();

    float* const plane = pwp + (size_t)kq * PWSZ;
#pragma unroll
    for (int i = 0; i < 4; ++i) {                    // wave w -> frags w*4+i
        const int f = w * 4 + i;
        const int g = f >> 2, h = f & 3;
        f32x4 v = lds[0][f][lane];
        v += lds[1][f][lane];
        v += lds[2][f][lane];
        v += lds[3][f][lane];
        const int orow = tr + g * 16 + hi * 4;
        const int ocol = tc + h * 16 + r;
#pragma unroll
        for (int e = 0; e < 4; ++e)
            plane[(orow + e) * BSZ + ocol] = v[e];
    }
}

// ---------------- Node 2: 4-anchor triplet reduce + de-contended finalize ---
// (R11 body; staging now sums the 4 K-quarter planes in fixed order.)
__global__ void __launch_bounds__(256) triplet_reduce(const float* __restrict__ pwp,
                                                      const int*   __restrict__ labels,
                                                      unsigned long long* __restrict__ part,
                                                      unsigned* __restrict__ ctr,
                                                      float* __restrict__ out) {
    __shared__ int   lab[BSZ];
    __shared__ float rows[4][BSZ];
    __shared__ float wsum_s[4];
    __shared__ int   wcnt_s[4];
    __shared__ unsigned is_last;

    const int tid  = threadIdx.x;
    const int lane = tid & 63;
    const int w    = tid >> 6;
    const int a0   = blockIdx.x * 4;

    if (tid < 128) ((int4*)lab)[tid] = ((const int4*)labels)[tid];
    {
        const float4* p0 = (const float4*)(pwp + 0 * (size_t)PWSZ + (size_t)a0 * BSZ);
        const float4* p1 = (const float4*)(pwp + 1 * (size_t)PWSZ + (size_t)a0 * BSZ);
        const float4* p2 = (const float4*)(pwp + 2 * (size_t)PWSZ + (size_t)a0 * BSZ);
        const float4* p3 = (const float4*)(pwp + 3 * (size_t)PWSZ + (size_t)a0 * BSZ);
#pragma unroll
        for (int j = 0; j < 2; ++j) {
            const int idx = tid + j * 256;           // 512 float4 = 4 rows
            float4 v = p0[idx];
            const float4 v1 = p1[idx], v2 = p2[idx], v3 = p3[idx];
            v.x += v1.x; v.y += v1.y; v.z += v1.z; v.w += v1.w;
            v.x += v2.x; v.y += v2.y; v.z += v2.z; v.w += v2.w;
            v.x += v3.x; v.y += v3.y; v.z += v3.z; v.w += v3.w;
            ((float4*)rows)[idx] = v;
        }
    }
    __syncthreads();

    const int la = lab[a0 + w];

    float vn[8];
    bool  ng[8];
#pragma unroll
    for (int j = 0; j < 8; ++j) {
        const int n = j * 64 + lane;
        vn[j] = rows[w][n];
        ng[j] = (lab[n] != la);
    }

    float sum = 0.f;
    int   cnt = 0;
    for (int p0 = 0; p0 < BSZ; p0 += 64) {
        unsigned long long m = __ballot(lab[p0 + lane] == la);
        while (m) {                                   // ascending p, uniform
            const int p = p0 + __ffsll((long long)m) - 1;
            m &= m - 1;
            const float pv = rows[w][p] + MARGIN;     // LDS broadcast
#pragma unroll
            for (int j = 0; j < 8; ++j) {
                const float v = pv - vn[j];
                sum += ng[j] ? fmaxf(v, 0.f) : 0.f;
                cnt += (ng[j] && v > EPSF) ? 1 : 0;
            }
        }
    }

#pragma unroll
    for (int off = 32; off > 0; off >>= 1) {
        sum += __shfl_down(sum, off);
        cnt += __shfl_down(cnt, off);
    }
    if (lane == 0) { wsum_s[w] = sum; wcnt_s[w] = cnt; }
    __syncthreads();

    if (tid == 0) {
        const float s = wsum_s[0] + wsum_s[1] + wsum_s[2] + wsum_s[3];
        const float c = (float)(wcnt_s[0] + wcnt_s[1] + wcnt_s[2] + wcnt_s[3]);
        const float2 pk2 = make_float2(s, c);
        __hip_atomic_store(&part[blockIdx.x],
                           __builtin_bit_cast(unsigned long long, pk2),
                           __ATOMIC_RELAXED, __HIP_MEMORY_SCOPE_AGENT);
        asm volatile("s_waitcnt vmcnt(0)" ::: "memory");   // store performed
        const unsigned old = __hip_atomic_fetch_add(ctr, 1u, __ATOMIC_RELAXED,
                                                    __HIP_MEMORY_SCOPE_AGENT);
        is_last = (old == (unsigned)(RBLK - 1)) ? 1u : 0u;
    }
    __syncthreads();

    if (is_last) {                                    // 128th block: finalize
        float s = 0.f, c = 0.f;
        if (tid < RBLK) {
            const unsigned long long v =
                __hip_atomic_load(&part[tid], __ATOMIC_RELAXED,
                                  __HIP_MEMORY_SCOPE_AGENT);
            const float2 f = __builtin_bit_cast(float2, v);
            s = f.x;
            c = f.y;
        }
#pragma unroll
        for (int off = 32; off > 0; off >>= 1) {
            s += __shfl_down(s, off);
            c += __shfl_down(c, off);
        }
        if (lane == 0) { wsum_s[w] = s; wcnt_s[w] = (int)c; }
        __syncthreads();
        if (tid == 0) {
            const float S_ = wsum_s[0] + wsum_s[1] + wsum_s[2] + wsum_s[3];
            const float C_ = (float)(wcnt_s[0] + wcnt_s[1] + wcnt_s[2] + wcnt_s[3]);
            out[0] = S_ / (C_ + EPSF);
        }
    }
}

extern "C" void kernel_launch(void* const* d_in, const int* in_sizes, int n_in,
                              void* d_out, int out_size, void* d_ws, size_t ws_size,
                              hipStream_t stream) {
    const int*   labels = (const int*)d_in[0];
    const float* img    = (const float*)d_in[1];
    const float* sen    = (const float*)d_in[2];
    float* out = (float*)d_out;

    // workspace: ctr (zeroed by node 1), pw partials 4 x 1 MB, partials (1 KB)
    unsigned*           ctr = (unsigned*)d_ws;
    float*              pwp = (float*)((char*)d_ws + 256);
    unsigned long long* part = (unsigned long long*)((char*)d_ws + 256 + 4 * (size_t)PWSZ * 4);

    mfma_gemm<<<256, 256, 0, stream>>>(img, sen, pwp, ctr);
    triplet_reduce<<<RBLK, 256, 0, stream>>>(pwp, labels, part, ctr, out);
}